// Round 14
// baseline (194.622 us; speedup 1.0000x reference)
//
#include <hip/hip_runtime.h>
#include <hip/hip_bf16.h>

#define BB 4
#define CC 2048
#define DD 1024
#define HH 16
#define HDD 64

typedef __attribute__((ext_vector_type(8))) short bf16x8;
typedef __attribute__((ext_vector_type(4))) float f32x4;
typedef __attribute__((ext_vector_type(16))) float f32x16;
typedef __attribute__((ext_vector_type(4))) unsigned short ushort4_t;
typedef __attribute__((ext_vector_type(4))) unsigned uint4v;

// (1/sqrt(64)) * log2(e): puts scores directly in exp2 domain
#define SCALE_LOG2E 0.18033688011112042f

__device__ __forceinline__ unsigned short f2bf(float f) {
  union { float f; unsigned u; } v; v.f = f;
  unsigned u = v.u;
  return (unsigned short)((u + 0x7fffu + ((u >> 16) & 1u)) >> 16);
}

__device__ __forceinline__ unsigned cvt_pk_bf16(float lo, float hi) {
  unsigned r;
  asm("v_cvt_pk_bf16_f32 %0, %1, %2" : "=v"(r) : "v"(lo), "v"(hi));
  return r;
}

__device__ __forceinline__ float shx32f(float x) { return __shfl_xor(x, 32, 64); }
__device__ __forceinline__ unsigned shx32u(unsigned x) {
  return (unsigned)__shfl_xor((int)x, 32, 64);
}

// async global -> LDS DMA, 16B per lane (dest = wave-uniform base + lane*16)
__device__ __forceinline__ void gload_lds16(const unsigned short* g, unsigned short* l) {
  __builtin_amdgcn_global_load_lds(
      (const __attribute__((address_space(1))) void*)g,
      (__attribute__((address_space(3))) void*)l, 16, 0, 0);
}

// ---------------------------------------------------------------------------
// Kernel 1: per-head QKV projection (unchanged, known-good).
// ---------------------------------------------------------------------------
__global__ __launch_bounds__(256) void qkv_proj_kernel(
    const float* __restrict__ x,
    const float* __restrict__ Wq, const float* __restrict__ bq,
    const float* __restrict__ Wk, const float* __restrict__ bk,
    const float* __restrict__ Wv, const float* __restrict__ bv,
    unsigned short* __restrict__ qo, unsigned short* __restrict__ ko,
    unsigned short* __restrict__ vto)
{
  const int blk = blockIdx.x;          // B*H*(C/128) = 1024
  const int ct = blk & 15;
  const int h  = (blk >> 4) & 15;
  const int b  = blk >> 8;
  const int wave = threadIdx.x >> 6;
  const int lane = threadIdx.x & 63;
  const int g = lane >> 4, l15 = lane & 15;

  const float* wqh = Wq + h * HDD * HDD;
  const float* wkh = Wk + h * HDD * HDD;
  const float* wvh = Wv + h * HDD * HDD;

  bf16x8 wqf[2][4], wkf[2][4], wvf[2][4];
  for (int c = 0; c < 2; ++c)
    for (int n = 0; n < 4; ++n) {
      const int e = 16 * n + l15;
      const int d0 = 32 * c + 8 * g;
      bf16x8 tq, tk, tv;
      for (int i = 0; i < 8; ++i) {
        tq[i] = (short)f2bf(wqh[(d0 + i) * HDD + e]);
        tk[i] = (short)f2bf(wkh[(d0 + i) * HDD + e]);
        tv[i] = (short)f2bf(wvh[(d0 + i) * HDD + e]);
      }
      wqf[c][n] = tq; wkf[c][n] = tk; wvf[c][n] = tv;
    }
  float bqv[4], bkv[4], bvv[4];
  for (int n = 0; n < 4; ++n) {
    bqv[n] = bq[h * HDD + 16 * n + l15];
    bkv[n] = bk[h * HDD + 16 * n + l15];
    bvv[n] = bv[h * HDD + 16 * n + l15];
  }

  const f32x4 fzero = {0.f, 0.f, 0.f, 0.f};
  const int c0 = ct * 128 + wave * 32;
  const int bh = b * HH + h;

  for (int mt = 0; mt < 2; ++mt) {
    const int crow_a = c0 + mt * 16 + l15;
    bf16x8 xa[2];
    for (int c = 0; c < 2; ++c) {
      const f32x4* xp = (const f32x4*)(x + (size_t)(b * CC + crow_a) * DD + h * HDD + 32 * c + 8 * g);
      f32x4 x0 = xp[0], x1 = xp[1];
      bf16x8 t;
      for (int i = 0; i < 4; ++i) { t[i] = (short)f2bf(x0[i]); t[4 + i] = (short)f2bf(x1[i]); }
      xa[c] = t;
    }
    f32x4 aq[4] = {fzero, fzero, fzero, fzero};
    f32x4 ak[4] = {fzero, fzero, fzero, fzero};
    f32x4 av[4] = {fzero, fzero, fzero, fzero};
    for (int c = 0; c < 2; ++c)
      for (int n = 0; n < 4; ++n) {
        aq[n] = __builtin_amdgcn_mfma_f32_16x16x32_bf16(xa[c], wqf[c][n], aq[n], 0, 0, 0);
        ak[n] = __builtin_amdgcn_mfma_f32_16x16x32_bf16(xa[c], wkf[c][n], ak[n], 0, 0, 0);
        av[n] = __builtin_amdgcn_mfma_f32_16x16x32_bf16(xa[c], wvf[c][n], av[n], 0, 0, 0);
      }
    const int crow_d = c0 + mt * 16 + 4 * g;
    for (int n = 0; n < 4; ++n) {
      const int e = 16 * n + l15;
      ushort4_t vpack;
      for (int r = 0; r < 4; ++r) {
        const int cr = crow_d + r;
        qo[((size_t)bh * CC + cr) * HDD + e] = f2bf((aq[n][r] + bqv[n]) * SCALE_LOG2E);
        ko[((size_t)bh * CC + cr) * HDD + e] = f2bf(ak[n][r] + bkv[n]);
        vpack[r] = f2bf(av[n][r] + bvv[n]);
      }
      *(ushort4_t*)(vto + ((size_t)bh * HDD + e) * CC + crow_d) = vpack;
    }
  }
}

// ---------------------------------------------------------------------------
// Kernel 2: flash attention — R13 structure (passed; XCD swizzle). Round-14
// sole change: the two independent FLASH32 sub-tiles of a superstep are
// fused into FLASH32PAIR with phase-interleaved program order (both QK
// clusters, then both softmaxes, then both exchanges, then both PV
// clusters). Two parallel dependency streams per wave hide the serial
// MFMA->exp2->pack->bpermute->MFMA chain. All formulas and within-stream
// operation order verbatim from R9/R13 -> bitwise-identical output.
// ---------------------------------------------------------------------------
#define STAGE(CUR, SS) do {                                                    \
  _Pragma("unroll") for (int _i = 0; _i < 4; ++_i)                             \
    gload_lds16(ssrc[_i] + (SS) * sadv[_i], sdst[_i] + (CUR) * 8192);          \
} while (0)

#define KREAD(DST, BASE, SUB) do {                                             \
  const int _row = (SUB) * 32 + l31;                                           \
  _Pragma("unroll") for (int _c = 0; _c < 4; ++_c)                             \
    DST[_c] = *(const bf16x8*)((BASE) + _row * 64 + (((2 * _c + hi) ^ (_row & 7)) * 8)); \
} while (0)

#define VREAD(DST, BASE, SUB) do {                                             \
  _Pragma("unroll") for (int _e = 0; _e < 2; ++_e)                             \
  _Pragma("unroll") for (int _t = 0; _t < 2; ++_t) {                           \
    const int _row = 32 * _e + l31;                                            \
    DST[_e * 2 + _t] = *(const bf16x8*)((BASE) + 4096 + _row * 64 +            \
                         (((4 * (SUB) + 2 * _t + hi) ^ (_row & 7)) * 8));      \
  }                                                                            \
} while (0)

#define FLASH32PAIR(KF0, VF0, KF1, VF1) do {                                   \
  f32x16 s0 = {}, s1 = {};                                                     \
  __builtin_amdgcn_s_setprio(1);                                               \
  _Pragma("unroll") for (int c = 0; c < 4; ++c)                                \
    s0 = __builtin_amdgcn_mfma_f32_32x32x16_bf16(KF0[c], qf[c], s0, 0, 0, 0);  \
  _Pragma("unroll") for (int c = 0; c < 4; ++c)                                \
    s1 = __builtin_amdgcn_mfma_f32_32x32x16_bf16(KF1[c], qf[c], s1, 0, 0, 0);  \
  __builtin_amdgcn_s_setprio(0);                                               \
  float p0[16], p1[16]; float rs0 = 0.f, rs1 = 0.f;                            \
  _Pragma("unroll") for (int i = 0; i < 16; ++i) {                             \
    p0[i] = __builtin_amdgcn_exp2f(s0[i]); rs0 += p0[i];                       \
  }                                                                            \
  _Pragma("unroll") for (int i = 0; i < 16; ++i) {                             \
    p1[i] = __builtin_amdgcn_exp2f(s1[i]); rs1 += p1[i];                       \
  }                                                                            \
  unsigned pa0 = cvt_pk_bf16(p0[0], p0[1]),  pb0 = cvt_pk_bf16(p0[2], p0[3]);  \
  unsigned pc0 = cvt_pk_bf16(p0[4], p0[5]),  pd0 = cvt_pk_bf16(p0[6], p0[7]);  \
  unsigned pe0 = cvt_pk_bf16(p0[8], p0[9]),  pf0 = cvt_pk_bf16(p0[10], p0[11]); \
  unsigned pg0 = cvt_pk_bf16(p0[12], p0[13]), ph0 = cvt_pk_bf16(p0[14], p0[15]); \
  unsigned pa1 = cvt_pk_bf16(p1[0], p1[1]),  pb1 = cvt_pk_bf16(p1[2], p1[3]);  \
  unsigned pc1 = cvt_pk_bf16(p1[4], p1[5]),  pd1 = cvt_pk_bf16(p1[6], p1[7]);  \
  unsigned pe1 = cvt_pk_bf16(p1[8], p1[9]),  pf1 = cvt_pk_bf16(p1[10], p1[11]); \
  unsigned pg1 = cvt_pk_bf16(p1[12], p1[13]), ph1 = cvt_pk_bf16(p1[14], p1[15]); \
  unsigned sa0 = shx32u(pa0), sb0 = shx32u(pb0), sc0 = shx32u(pc0), sd0 = shx32u(pd0); \
  unsigned se0 = shx32u(pe0), sf0 = shx32u(pf0), sg0 = shx32u(pg0), sh0 = shx32u(ph0); \
  unsigned sa1 = shx32u(pa1), sb1 = shx32u(pb1), sc1 = shx32u(pc1), sd1 = shx32u(pd1); \
  unsigned se1 = shx32u(pe1), sf1 = shx32u(pf1), sg1 = shx32u(pg1), sh1 = shx32u(ph1); \
  uint4v u00 = {hi ? sc0 : pa0, hi ? sd0 : pb0, hi ? pc0 : sa0, hi ? pd0 : sb0}; \
  uint4v u01 = {hi ? sg0 : pe0, hi ? sh0 : pf0, hi ? pg0 : se0, hi ? ph0 : sf0}; \
  uint4v u10 = {hi ? sc1 : pa1, hi ? sd1 : pb1, hi ? pc1 : sa1, hi ? pd1 : sb1}; \
  uint4v u11 = {hi ? sg1 : pe1, hi ? sh1 : pf1, hi ? pg1 : se1, hi ? ph1 : sf1}; \
  bf16x8 pfr00 = __builtin_bit_cast(bf16x8, u00);                              \
  bf16x8 pfr01 = __builtin_bit_cast(bf16x8, u01);                              \
  bf16x8 pfr10 = __builtin_bit_cast(bf16x8, u10);                              \
  bf16x8 pfr11 = __builtin_bit_cast(bf16x8, u11);                              \
  rs0 += shx32f(rs0);                                                          \
  l += rs0;                                                                    \
  rs1 += shx32f(rs1);                                                          \
  l += rs1;                                                                    \
  __builtin_amdgcn_s_setprio(1);                                               \
  acc0 = __builtin_amdgcn_mfma_f32_32x32x16_bf16(VF0[0], pfr00, acc0, 0, 0, 0); \
  acc0 = __builtin_amdgcn_mfma_f32_32x32x16_bf16(VF0[1], pfr01, acc0, 0, 0, 0); \
  acc1 = __builtin_amdgcn_mfma_f32_32x32x16_bf16(VF0[2], pfr00, acc1, 0, 0, 0); \
  acc1 = __builtin_amdgcn_mfma_f32_32x32x16_bf16(VF0[3], pfr01, acc1, 0, 0, 0); \
  acc0 = __builtin_amdgcn_mfma_f32_32x32x16_bf16(VF1[0], pfr10, acc0, 0, 0, 0); \
  acc0 = __builtin_amdgcn_mfma_f32_32x32x16_bf16(VF1[1], pfr11, acc0, 0, 0, 0); \
  acc1 = __builtin_amdgcn_mfma_f32_32x32x16_bf16(VF1[2], pfr10, acc1, 0, 0, 0); \
  acc1 = __builtin_amdgcn_mfma_f32_32x32x16_bf16(VF1[3], pfr11, acc1, 0, 0, 0); \
  __builtin_amdgcn_s_setprio(0);                                               \
} while (0)

__global__ __launch_bounds__(256, 2) void flash_fwd_kernel(
    const unsigned short* __restrict__ qw, const unsigned short* __restrict__ kw,
    const unsigned short* __restrict__ vtw,
    float* __restrict__ out, float* __restrict__ lse)
{
  __shared__ __align__(16) unsigned short slds[2][8192];   // 2 x (K 8KB | V 8KB)
  // XCD-chunked remap: grid 1024, 8 XCDs, 128 blocks/XCD chunk (bijective)
  const int blk = (blockIdx.x & 7) * 128 + (blockIdx.x >> 3);
  const int qt = blk & 15;
  const int h  = (blk >> 4) & 15;
  const int b  = blk >> 8;
  const int wave = threadIdx.x >> 6;
  const int lane = threadIdx.x & 63;
  const int l31 = lane & 31, hi = lane >> 5;
  const int bh = b * HH + h;
  const int q0 = qt * 128 + wave * 32;

  const unsigned short* qbh = qw + (size_t)bh * CC * HDD;
  const unsigned short* kbh = kw + (size_t)bh * CC * HDD;
  const unsigned short* vbh = vtw + (size_t)bh * HDD * CC;

  bf16x8 qf[4];
  for (int c = 0; c < 4; ++c)
    qf[c] = *(const bf16x8*)(qbh + (q0 + l31) * HDD + 16 * c + 8 * hi);

  const unsigned short* ssrc[4];
  int sadv[4];
  unsigned short* sdst[4];
#pragma unroll
  for (int i = 0; i < 4; ++i) {
    const int L = (wave * 4 + i) * 1024 + lane * 16;   // byte in 16KB tile
    const int tile = L >> 13;                           // 0 = K, 1 = V
    const int t = L & 8191;
    const int row = t >> 7;
    const int sch = ((t >> 4) & 7) ^ (row & 7);
    if (tile == 0) { ssrc[i] = kbh + row * HDD + sch * 8;        sadv[i] = 64 * HDD; }
    else           { ssrc[i] = vbh + (size_t)row * CC + sch * 8; sadv[i] = 64; }
    sdst[i] = &slds[0][0] + (wave * 4 + i) * 512;      // ushort units (1KB)
  }

  f32x16 acc0 = {}, acc1 = {};
  float l = 0.f;

  STAGE(0, 0);
  __syncthreads();
  int cur = 0;
  for (int ss = 0; ss < 32; ++ss) {
    if (ss != 31) STAGE(cur ^ 1, ss + 1);
    const unsigned short* base = &slds[0][0] + cur * 8192;
    bf16x8 kf0[4], vf0[4], kf1[4], vf1[4];
    KREAD(kf0, base, 0);
    VREAD(vf0, base, 0);
    KREAD(kf1, base, 1);
    VREAD(vf1, base, 1);
    FLASH32PAIR(kf0, vf0, kf1, vf1);
    __syncthreads();
    cur ^= 1;
  }

  const float rl = __builtin_amdgcn_rcpf(l);
  for (int i = 0; i < 16; ++i) { acc0[i] *= rl; acc1[i] *= rl; }
  float* orow = out + (size_t)(b * CC + q0 + l31) * DD + h * HDD;
  for (int j = 0; j < 4; ++j) {
    f32x4 v0, v1;
    for (int t = 0; t < 4; ++t) { v0[t] = acc0[4 * j + t]; v1[t] = acc1[4 * j + t]; }
    *(f32x4*)(orow + 4 * hi + 8 * j) = v0;
    *(f32x4*)(orow + 32 + 4 * hi + 8 * j) = v1;
  }
  if (hi == 0)
    lse[(size_t)bh * CC + q0 + l31] = __builtin_amdgcn_logf(l) + 4.0f;  // + log2(H)
}

// ---------------------------------------------------------------------------
// Kernel 3: attn_mean (unchanged from round 13, verified).
// ---------------------------------------------------------------------------
#define AMK_LDSU 20480  // ushorts per buffer: K 16384 + Q 4096

#define ASTAGE(BUF, H) do {                                                    \
  _Pragma("unroll") for (int _i = 0; _i < 10; ++_i)                            \
    gload_lds16(asrc[_i] + (size_t)(H) * (CC * HDD), adst[_i] + (BUF) * AMK_LDSU); \
} while (0)

#define ATILE(QF, KF, AP, LS) do {                                             \
  f32x16 s_ = {};                                                              \
  _Pragma("unroll") for (int c = 0; c < 4; ++c)                                \
    s_ = __builtin_amdgcn_mfma_f32_32x32x16_bf16(QF[c], KF[c], s_, 0, 0, 0);   \
  _Pragma("unroll") for (int r = 0; r < 16; ++r)                               \
    AP[r] += __builtin_amdgcn_exp2f(s_[r] - LS[r]);                            \
} while (0)

__global__ __launch_bounds__(256, 2) void attn_mean_kernel(
    const unsigned short* __restrict__ qw, const unsigned short* __restrict__ kw,
    const float* __restrict__ lse, float* __restrict__ amean)
{
  __shared__ __align__(16) unsigned short slds[2][AMK_LDSU];
  // XCD-chunked remap: grid 1024 (bijective)
  const int blk = (blockIdx.x & 7) * 128 + (blockIdx.x >> 3);
  const int kvg = blk & 7;
  const int qt  = (blk >> 3) & 31;
  const int b   = blk >> 8;
  const int tid  = threadIdx.x;
  const int wave = tid >> 6;
  const int lane = tid & 63;
  const int l31 = lane & 31, hi = lane >> 5;
  const int q0 = qt * 64;
  const int kvb = kvg * 256;
  const int kv0 = kvb + wave * 64;

  const unsigned short* qb0 = qw + (size_t)(b * HH) * CC * HDD;  // head 0
  const unsigned short* kb0 = kw + (size_t)(b * HH) * CC * HDD;

  const unsigned short* asrc[10];
  unsigned short* adst[10];
#pragma unroll
  for (int i = 0; i < 10; ++i) {
    const int L = (i * 256 + tid) * 16;        // byte offset in 40KB tile
    if (L < 32768) {                            // K region: row=kvb+L/128
      const int row = L >> 7;
      const int ch = ((L >> 4) & 7) ^ (row & 7);
      asrc[i] = kb0 + (kvb + row) * HDD + ch * 8;
    } else {                                    // Q region: row=q0+Lq/128
      const int Lq = L - 32768;
      const int row = Lq >> 7;
      const int ch = ((Lq >> 4) & 7) ^ (row & 7);
      asrc[i] = qb0 + (q0 + row) * HDD + ch * 8;
    }
    adst[i] = &slds[0][0] + i * 2048 + wave * 512;   // ushort units
  }

  f32x16 ap00 = {}, ap01 = {}, ap10 = {}, ap11 = {};

  ASTAGE(0, 0);
  __syncthreads();
  int cur = 0;
  for (int h = 0; h < HH; ++h) {
    if (h != HH - 1) ASTAGE(cur ^ 1, h + 1);
    const float* lp = lse + (size_t)(b * HH + h) * CC + q0;
    float ls0[16], ls1[16];
#pragma unroll
    for (int r = 0; r < 16; ++r) {
      const int qr = (r & 3) + 8 * (r >> 2) + 4 * hi;
      ls0[r] = lp[qr];
      ls1[r] = lp[32 + qr];
    }
    const unsigned short* base = &slds[0][0] + cur * AMK_LDSU;
    bf16x8 qf0[4], qf1[4], kf0[4], kf1[4];
#pragma unroll
    for (int c = 0; c < 4; ++c) {
      const int qrow0 = l31, qrow1 = 32 + l31;
      const int krow0 = wave * 64 + l31, krow1 = wave * 64 + 32 + l31;
      qf0[c] = *(const bf16x8*)(base + 16384 + qrow0 * 64 + (((2 * c + hi) ^ (qrow0 & 7)) * 8));
      qf1[c] = *(const bf16x8*)(base + 16384 + qrow1 * 64 + (((2 * c + hi) ^ (qrow1 & 7)) * 8));
      kf0[c] = *(const bf16x8*)(base + krow0 * 64 + (((2 * c + hi) ^ (krow0 & 7)) * 8));
      kf1[c] = *(const bf16x8*)(base + krow1 * 64 + (((2 * c + hi) ^ (krow1 & 7)) * 8));
    }
    ATILE(qf0, kf0, ap00, ls0);
    ATILE(qf0, kf1, ap01, ls0);
    ATILE(qf1, kf0, ap10, ls1);
    ATILE(qf1, kf1, ap11, ls1);
    __syncthreads();
    cur ^= 1;
  }

  for (int r = 0; r < 16; ++r) {
    const int qr = (r & 3) + 8 * (r >> 2) + 4 * hi;
    const size_t row0 = (size_t)(b * CC + q0 + qr) * CC;
    const size_t row1 = row0 + (size_t)32 * CC;
    amean[row0 + kv0 + l31] = ap00[r];
    amean[row0 + kv0 + 32 + l31] = ap01[r];
    amean[row1 + kv0 + l31] = ap10[r];
    amean[row1 + kv0 + 32 + l31] = ap11[r];
  }
}

extern "C" void kernel_launch(void* const* d_in, const int* in_sizes, int n_in,
                              void* d_out, int out_size, void* d_ws, size_t ws_size,
                              hipStream_t stream) {
  const float* x  = (const float*)d_in[0];
  const float* Wq = (const float*)d_in[1];
  const float* bq = (const float*)d_in[2];
  const float* Wk = (const float*)d_in[3];
  const float* bk = (const float*)d_in[4];
  const float* Wv = (const float*)d_in[5];
  const float* bv = (const float*)d_in[6];
  float* out = (float*)d_out;
  float* amean = out + (size_t)BB * CC * DD;

  const size_t nqkv = (size_t)BB * HH * CC * HDD;
  unsigned short* qws  = (unsigned short*)d_ws;
  unsigned short* kws  = qws + nqkv;
  unsigned short* vtws = kws + nqkv;
  float* lse = (float*)(vtws + nqkv);

  qkv_proj_kernel<<<BB * HH * (CC / 128), 256, 0, stream>>>(
      x, Wq, bq, Wk, bk, Wv, bv, qws, kws, vtws);
  flash_fwd_kernel<<<BB * HH * (CC / 128), 256, 0, stream>>>(
      qws, kws, vtws, out, lse);
  attn_mean_kernel<<<BB * (CC / 64) * (CC / 256), 256, 0, stream>>>(
      qws, kws, lse, amean);
}

// Round 16
// 190.920 us; speedup vs baseline: 1.0194x; 1.0194x over previous
//
#include <hip/hip_runtime.h>
#include <hip/hip_bf16.h>

#define BB 4
#define CC 2048
#define DD 1024
#define HH 16
#define HDD 64

typedef __attribute__((ext_vector_type(8))) short bf16x8;
typedef __attribute__((ext_vector_type(4))) float f32x4;
typedef __attribute__((ext_vector_type(16))) float f32x16;
typedef __attribute__((ext_vector_type(4))) unsigned short ushort4_t;
typedef __attribute__((ext_vector_type(4))) unsigned uint4v;

// (1/sqrt(64)) * log2(e): puts scores directly in exp2 domain
#define SCALE_LOG2E 0.18033688011112042f

// explicit DMA drain: each wave's global_load_lds writes are tracked by its
// own vmcnt; cross-wave visibility of a staged LDS buffer requires vmcnt(0)
// before the barrier. The compiler normally emits this; we make it explicit
// so codegen variations can never drop it (suspected cause of the R15 fail).
#define DRAIN asm volatile("s_waitcnt vmcnt(0)" ::: "memory")

__device__ __forceinline__ unsigned short f2bf(float f) {
  union { float f; unsigned u; } v; v.f = f;
  unsigned u = v.u;
  return (unsigned short)((u + 0x7fffu + ((u >> 16) & 1u)) >> 16);
}

__device__ __forceinline__ unsigned cvt_pk_bf16(float lo, float hi) {
  unsigned r;
  asm("v_cvt_pk_bf16_f32 %0, %1, %2" : "=v"(r) : "v"(lo), "v"(hi));
  return r;
}

__device__ __forceinline__ float shx32f(float x) { return __shfl_xor(x, 32, 64); }
__device__ __forceinline__ unsigned shx32u(unsigned x) {
  return (unsigned)__shfl_xor((int)x, 32, 64);
}

// async global -> LDS DMA, 16B per lane (dest = wave-uniform base + lane*16)
__device__ __forceinline__ void gload_lds16(const unsigned short* g, unsigned short* l) {
  __builtin_amdgcn_global_load_lds(
      (const __attribute__((address_space(1))) void*)g,
      (__attribute__((address_space(3))) void*)l, 16, 0, 0);
}

// ---------------------------------------------------------------------------
// Kernel 1: per-head QKV projection (unchanged, known-good).
// ---------------------------------------------------------------------------
__global__ __launch_bounds__(256) void qkv_proj_kernel(
    const float* __restrict__ x,
    const float* __restrict__ Wq, const float* __restrict__ bq,
    const float* __restrict__ Wk, const float* __restrict__ bk,
    const float* __restrict__ Wv, const float* __restrict__ bv,
    unsigned short* __restrict__ qo, unsigned short* __restrict__ ko,
    unsigned short* __restrict__ vto)
{
  const int blk = blockIdx.x;          // B*H*(C/128) = 1024
  const int ct = blk & 15;
  const int h  = (blk >> 4) & 15;
  const int b  = blk >> 8;
  const int wave = threadIdx.x >> 6;
  const int lane = threadIdx.x & 63;
  const int g = lane >> 4, l15 = lane & 15;

  const float* wqh = Wq + h * HDD * HDD;
  const float* wkh = Wk + h * HDD * HDD;
  const float* wvh = Wv + h * HDD * HDD;

  bf16x8 wqf[2][4], wkf[2][4], wvf[2][4];
  for (int c = 0; c < 2; ++c)
    for (int n = 0; n < 4; ++n) {
      const int e = 16 * n + l15;
      const int d0 = 32 * c + 8 * g;
      bf16x8 tq, tk, tv;
      for (int i = 0; i < 8; ++i) {
        tq[i] = (short)f2bf(wqh[(d0 + i) * HDD + e]);
        tk[i] = (short)f2bf(wkh[(d0 + i) * HDD + e]);
        tv[i] = (short)f2bf(wvh[(d0 + i) * HDD + e]);
      }
      wqf[c][n] = tq; wkf[c][n] = tk; wvf[c][n] = tv;
    }
  float bqv[4], bkv[4], bvv[4];
  for (int n = 0; n < 4; ++n) {
    bqv[n] = bq[h * HDD + 16 * n + l15];
    bkv[n] = bk[h * HDD + 16 * n + l15];
    bvv[n] = bv[h * HDD + 16 * n + l15];
  }

  const f32x4 fzero = {0.f, 0.f, 0.f, 0.f};
  const int c0 = ct * 128 + wave * 32;
  const int bh = b * HH + h;

  for (int mt = 0; mt < 2; ++mt) {
    const int crow_a = c0 + mt * 16 + l15;
    bf16x8 xa[2];
    for (int c = 0; c < 2; ++c) {
      const f32x4* xp = (const f32x4*)(x + (size_t)(b * CC + crow_a) * DD + h * HDD + 32 * c + 8 * g);
      f32x4 x0 = xp[0], x1 = xp[1];
      bf16x8 t;
      for (int i = 0; i < 4; ++i) { t[i] = (short)f2bf(x0[i]); t[4 + i] = (short)f2bf(x1[i]); }
      xa[c] = t;
    }
    f32x4 aq[4] = {fzero, fzero, fzero, fzero};
    f32x4 ak[4] = {fzero, fzero, fzero, fzero};
    f32x4 av[4] = {fzero, fzero, fzero, fzero};
    for (int c = 0; c < 2; ++c)
      for (int n = 0; n < 4; ++n) {
        aq[n] = __builtin_amdgcn_mfma_f32_16x16x32_bf16(xa[c], wqf[c][n], aq[n], 0, 0, 0);
        ak[n] = __builtin_amdgcn_mfma_f32_16x16x32_bf16(xa[c], wkf[c][n], ak[n], 0, 0, 0);
        av[n] = __builtin_amdgcn_mfma_f32_16x16x32_bf16(xa[c], wvf[c][n], av[n], 0, 0, 0);
      }
    const int crow_d = c0 + mt * 16 + 4 * g;
    for (int n = 0; n < 4; ++n) {
      const int e = 16 * n + l15;
      ushort4_t vpack;
      for (int r = 0; r < 4; ++r) {
        const int cr = crow_d + r;
        qo[((size_t)bh * CC + cr) * HDD + e] = f2bf((aq[n][r] + bqv[n]) * SCALE_LOG2E);
        ko[((size_t)bh * CC + cr) * HDD + e] = f2bf(ak[n][r] + bkv[n]);
        vpack[r] = f2bf(av[n][r] + bvv[n]);
      }
      *(ushort4_t*)(vto + ((size_t)bh * HDD + e) * CC + crow_d) = vpack;
    }
  }
}

// ---------------------------------------------------------------------------
// Kernel 2: flash attention — EXACT R13 body (passed at 191.3us) plus the
// explicit DRAIN before each barrier (race-window closure; no-op if the
// compiler already emits the vmcnt(0) drain).
// ---------------------------------------------------------------------------
#define STAGE(CUR, SS) do {                                                    \
  _Pragma("unroll") for (int _i = 0; _i < 4; ++_i)                             \
    gload_lds16(ssrc[_i] + (SS) * sadv[_i], sdst[_i] + (CUR) * 8192);          \
} while (0)

#define KREAD(DST, BASE, SUB) do {                                             \
  const int _row = (SUB) * 32 + l31;                                           \
  _Pragma("unroll") for (int _c = 0; _c < 4; ++_c)                             \
    DST[_c] = *(const bf16x8*)((BASE) + _row * 64 + (((2 * _c + hi) ^ (_row & 7)) * 8)); \
} while (0)

#define VREAD(DST, BASE, SUB) do {                                             \
  _Pragma("unroll") for (int _e = 0; _e < 2; ++_e)                             \
  _Pragma("unroll") for (int _t = 0; _t < 2; ++_t) {                           \
    const int _row = 32 * _e + l31;                                            \
    DST[_e * 2 + _t] = *(const bf16x8*)((BASE) + 4096 + _row * 64 +            \
                         (((4 * (SUB) + 2 * _t + hi) ^ (_row & 7)) * 8));      \
  }                                                                            \
} while (0)

#define FLASH32(KF, VF) do {                                                   \
  f32x16 s = {};                                                               \
  __builtin_amdgcn_s_setprio(1);                                               \
  _Pragma("unroll") for (int c = 0; c < 4; ++c)                                \
    s = __builtin_amdgcn_mfma_f32_32x32x16_bf16(KF[c], qf[c], s, 0, 0, 0);     \
  __builtin_amdgcn_s_setprio(0);                                               \
  float p[16]; float rs = 0.f;                                                 \
  _Pragma("unroll") for (int i = 0; i < 16; ++i) {                             \
    p[i] = __builtin_amdgcn_exp2f(s[i]); rs += p[i];                           \
  }                                                                            \
  unsigned pa = cvt_pk_bf16(p[0], p[1]),  pb = cvt_pk_bf16(p[2], p[3]);        \
  unsigned pc = cvt_pk_bf16(p[4], p[5]),  pd = cvt_pk_bf16(p[6], p[7]);        \
  unsigned pe = cvt_pk_bf16(p[8], p[9]),  pf_ = cvt_pk_bf16(p[10], p[11]);     \
  unsigned pg = cvt_pk_bf16(p[12], p[13]), ph = cvt_pk_bf16(p[14], p[15]);     \
  unsigned spa = shx32u(pa), spb = shx32u(pb), spc = shx32u(pc), spd = shx32u(pd); \
  unsigned spe = shx32u(pe), spf = shx32u(pf_), spg = shx32u(pg), sph = shx32u(ph); \
  unsigned w00 = hi ? spc : pa, w01 = hi ? spd : pb;                           \
  unsigned w02 = hi ? pc : spa, w03 = hi ? pd : spb;                           \
  unsigned w10 = hi ? spg : pe, w11 = hi ? sph : pf_;                          \
  unsigned w12 = hi ? pg : spe, w13 = hi ? ph : spf;                           \
  uint4v u0 = {w00, w01, w02, w03}, u1 = {w10, w11, w12, w13};                 \
  bf16x8 pfr0 = __builtin_bit_cast(bf16x8, u0);                                \
  bf16x8 pfr1 = __builtin_bit_cast(bf16x8, u1);                                \
  rs += shx32f(rs);                                                            \
  l += rs;                                                                     \
  __builtin_amdgcn_s_setprio(1);                                               \
  acc0 = __builtin_amdgcn_mfma_f32_32x32x16_bf16(VF[0], pfr0, acc0, 0, 0, 0);  \
  acc0 = __builtin_amdgcn_mfma_f32_32x32x16_bf16(VF[1], pfr1, acc0, 0, 0, 0);  \
  acc1 = __builtin_amdgcn_mfma_f32_32x32x16_bf16(VF[2], pfr0, acc1, 0, 0, 0);  \
  acc1 = __builtin_amdgcn_mfma_f32_32x32x16_bf16(VF[3], pfr1, acc1, 0, 0, 0);  \
  __builtin_amdgcn_s_setprio(0);                                               \
} while (0)

__global__ __launch_bounds__(256, 2) void flash_fwd_kernel(
    const unsigned short* __restrict__ qw, const unsigned short* __restrict__ kw,
    const unsigned short* __restrict__ vtw,
    float* __restrict__ out, float* __restrict__ lse)
{
  __shared__ __align__(16) unsigned short slds[2][8192];   // 2 x (K 8KB | V 8KB)
  // XCD-chunked remap: grid 1024, 8 XCDs, 128 blocks/XCD chunk (bijective)
  const int blk = (blockIdx.x & 7) * 128 + (blockIdx.x >> 3);
  const int qt = blk & 15;
  const int h  = (blk >> 4) & 15;
  const int b  = blk >> 8;
  const int wave = threadIdx.x >> 6;
  const int lane = threadIdx.x & 63;
  const int l31 = lane & 31, hi = lane >> 5;
  const int bh = b * HH + h;
  const int q0 = qt * 128 + wave * 32;

  const unsigned short* qbh = qw + (size_t)bh * CC * HDD;
  const unsigned short* kbh = kw + (size_t)bh * CC * HDD;
  const unsigned short* vbh = vtw + (size_t)bh * HDD * CC;

  bf16x8 qf[4];
  for (int c = 0; c < 4; ++c)
    qf[c] = *(const bf16x8*)(qbh + (q0 + l31) * HDD + 16 * c + 8 * hi);

  const unsigned short* ssrc[4];
  int sadv[4];
  unsigned short* sdst[4];
#pragma unroll
  for (int i = 0; i < 4; ++i) {
    const int L = (wave * 4 + i) * 1024 + lane * 16;   // byte in 16KB tile
    const int tile = L >> 13;                           // 0 = K, 1 = V
    const int t = L & 8191;
    const int row = t >> 7;
    const int sch = ((t >> 4) & 7) ^ (row & 7);
    if (tile == 0) { ssrc[i] = kbh + row * HDD + sch * 8;        sadv[i] = 64 * HDD; }
    else           { ssrc[i] = vbh + (size_t)row * CC + sch * 8; sadv[i] = 64; }
    sdst[i] = &slds[0][0] + (wave * 4 + i) * 512;      // ushort units (1KB)
  }

  f32x16 acc0 = {}, acc1 = {};
  float l = 0.f;

  STAGE(0, 0);
  DRAIN;
  __syncthreads();
  int cur = 0;
  for (int ss = 0; ss < 32; ++ss) {
    if (ss != 31) STAGE(cur ^ 1, ss + 1);
    const unsigned short* base = &slds[0][0] + cur * 8192;
    bf16x8 kf[4], vf[4];
    KREAD(kf, base, 0);
    VREAD(vf, base, 0);
    FLASH32(kf, vf);
    KREAD(kf, base, 1);
    VREAD(vf, base, 1);
    FLASH32(kf, vf);
    DRAIN;
    __syncthreads();
    cur ^= 1;
  }

  const float rl = __builtin_amdgcn_rcpf(l);
  for (int i = 0; i < 16; ++i) { acc0[i] *= rl; acc1[i] *= rl; }
  float* orow = out + (size_t)(b * CC + q0 + l31) * DD + h * HDD;
  for (int j = 0; j < 4; ++j) {
    f32x4 v0, v1;
    for (int t = 0; t < 4; ++t) { v0[t] = acc0[4 * j + t]; v1[t] = acc1[4 * j + t]; }
    *(f32x4*)(orow + 4 * hi + 8 * j) = v0;
    *(f32x4*)(orow + 32 + 4 * hi + 8 * j) = v1;
  }
  if (hi == 0)
    lse[(size_t)bh * CC + q0 + l31] = __builtin_amdgcn_logf(l) + 4.0f;  // + log2(H)
}

// ---------------------------------------------------------------------------
// Kernel 3: attn_mean — EXACT R13 body plus explicit DRAIN before barriers.
// ---------------------------------------------------------------------------
#define AMK_LDSU 20480  // ushorts per buffer: K 16384 + Q 4096

#define ASTAGE(BUF, H) do {                                                    \
  _Pragma("unroll") for (int _i = 0; _i < 10; ++_i)                            \
    gload_lds16(asrc[_i] + (size_t)(H) * (CC * HDD), adst[_i] + (BUF) * AMK_LDSU); \
} while (0)

#define ATILE(QF, KF, AP, LS) do {                                             \
  f32x16 s_ = {};                                                              \
  _Pragma("unroll") for (int c = 0; c < 4; ++c)                                \
    s_ = __builtin_amdgcn_mfma_f32_32x32x16_bf16(QF[c], KF[c], s_, 0, 0, 0);   \
  _Pragma("unroll") for (int r = 0; r < 16; ++r)                               \
    AP[r] += __builtin_amdgcn_exp2f(s_[r] - LS[r]);                            \
} while (0)

__global__ __launch_bounds__(256, 2) void attn_mean_kernel(
    const unsigned short* __restrict__ qw, const unsigned short* __restrict__ kw,
    const float* __restrict__ lse, float* __restrict__ amean)
{
  __shared__ __align__(16) unsigned short slds[2][AMK_LDSU];
  // XCD-chunked remap: grid 1024 (bijective)
  const int blk = (blockIdx.x & 7) * 128 + (blockIdx.x >> 3);
  const int kvg = blk & 7;
  const int qt  = (blk >> 3) & 31;
  const int b   = blk >> 8;
  const int tid  = threadIdx.x;
  const int wave = tid >> 6;
  const int lane = tid & 63;
  const int l31 = lane & 31, hi = lane >> 5;
  const int q0 = qt * 64;
  const int kvb = kvg * 256;
  const int kv0 = kvb + wave * 64;

  const unsigned short* qb0 = qw + (size_t)(b * HH) * CC * HDD;  // head 0
  const unsigned short* kb0 = kw + (size_t)(b * HH) * CC * HDD;

  const unsigned short* asrc[10];
  unsigned short* adst[10];
#pragma unroll
  for (int i = 0; i < 10; ++i) {
    const int L = (i * 256 + tid) * 16;        // byte offset in 40KB tile
    if (L < 32768) {                            // K region: row=kvb+L/128
      const int row = L >> 7;
      const int ch = ((L >> 4) & 7) ^ (row & 7);
      asrc[i] = kb0 + (kvb + row) * HDD + ch * 8;
    } else {                                    // Q region: row=q0+Lq/128
      const int Lq = L - 32768;
      const int row = Lq >> 7;
      const int ch = ((Lq >> 4) & 7) ^ (row & 7);
      asrc[i] = qb0 + (q0 + row) * HDD + ch * 8;
    }
    adst[i] = &slds[0][0] + i * 2048 + wave * 512;   // ushort units
  }

  f32x16 ap00 = {}, ap01 = {}, ap10 = {}, ap11 = {};

  ASTAGE(0, 0);
  DRAIN;
  __syncthreads();
  int cur = 0;
  for (int h = 0; h < HH; ++h) {
    if (h != HH - 1) ASTAGE(cur ^ 1, h + 1);
    const float* lp = lse + (size_t)(b * HH + h) * CC + q0;
    float ls0[16], ls1[16];
#pragma unroll
    for (int r = 0; r < 16; ++r) {
      const int qr = (r & 3) + 8 * (r >> 2) + 4 * hi;
      ls0[r] = lp[qr];
      ls1[r] = lp[32 + qr];
    }
    const unsigned short* base = &slds[0][0] + cur * AMK_LDSU;
    bf16x8 qf0[4], qf1[4], kf0[4], kf1[4];
#pragma unroll
    for (int c = 0; c < 4; ++c) {
      const int qrow0 = l31, qrow1 = 32 + l31;
      const int krow0 = wave * 64 + l31, krow1 = wave * 64 + 32 + l31;
      qf0[c] = *(const bf16x8*)(base + 16384 + qrow0 * 64 + (((2 * c + hi) ^ (qrow0 & 7)) * 8));
      qf1[c] = *(const bf16x8*)(base + 16384 + qrow1 * 64 + (((2 * c + hi) ^ (qrow1 & 7)) * 8));
      kf0[c] = *(const bf16x8*)(base + krow0 * 64 + (((2 * c + hi) ^ (krow0 & 7)) * 8));
      kf1[c] = *(const bf16x8*)(base + krow1 * 64 + (((2 * c + hi) ^ (krow1 & 7)) * 8));
    }
    ATILE(qf0, kf0, ap00, ls0);
    ATILE(qf0, kf1, ap01, ls0);
    ATILE(qf1, kf0, ap10, ls1);
    ATILE(qf1, kf1, ap11, ls1);
    DRAIN;
    __syncthreads();
    cur ^= 1;
  }

  for (int r = 0; r < 16; ++r) {
    const int qr = (r & 3) + 8 * (r >> 2) + 4 * hi;
    const size_t row0 = (size_t)(b * CC + q0 + qr) * CC;
    const size_t row1 = row0 + (size_t)32 * CC;
    amean[row0 + kv0 + l31] = ap00[r];
    amean[row0 + kv0 + 32 + l31] = ap01[r];
    amean[row1 + kv0 + l31] = ap10[r];
    amean[row1 + kv0 + 32 + l31] = ap11[r];
  }
}

extern "C" void kernel_launch(void* const* d_in, const int* in_sizes, int n_in,
                              void* d_out, int out_size, void* d_ws, size_t ws_size,
                              hipStream_t stream) {
  const float* x  = (const float*)d_in[0];
  const float* Wq = (const float*)d_in[1];
  const float* bq = (const float*)d_in[2];
  const float* Wk = (const float*)d_in[3];
  const float* bk = (const float*)d_in[4];
  const float* Wv = (const float*)d_in[5];
  const float* bv = (const float*)d_in[6];
  float* out = (float*)d_out;
  float* amean = out + (size_t)BB * CC * DD;

  const size_t nqkv = (size_t)BB * HH * CC * HDD;
  unsigned short* qws  = (unsigned short*)d_ws;
  unsigned short* kws  = qws + nqkv;
  unsigned short* vtws = kws + nqkv;
  float* lse = (float*)(vtws + nqkv);

  qkv_proj_kernel<<<BB * HH * (CC / 128), 256, 0, stream>>>(
      x, Wq, bq, Wk, bk, Wv, bv, qws, kws, vtws);
  flash_fwd_kernel<<<BB * HH * (CC / 128), 256, 0, stream>>>(
      qws, kws, vtws, out, lse);
  attn_mean_kernel<<<BB * (CC / 64) * (CC / 256), 256, 0, stream>>>(
      qws, kws, lse, amean);
}

// Round 17
// 188.862 us; speedup vs baseline: 1.0305x; 1.0109x over previous
//
#include <hip/hip_runtime.h>
#include <hip/hip_bf16.h>

#define BB 4
#define CC 2048
#define DD 1024
#define HH 16
#define HDD 64

typedef __attribute__((ext_vector_type(8))) short bf16x8;
typedef __attribute__((ext_vector_type(4))) float f32x4;
typedef __attribute__((ext_vector_type(16))) float f32x16;
typedef __attribute__((ext_vector_type(4))) unsigned short ushort4_t;
typedef __attribute__((ext_vector_type(4))) unsigned uint4v;

// (1/sqrt(64)) * log2(e): puts scores directly in exp2 domain
#define SCALE_LOG2E 0.18033688011112042f

// explicit DMA drain: each wave's global_load_lds writes are tracked by its
// own vmcnt; cross-wave visibility of a staged LDS buffer requires vmcnt(0)
// before the barrier. Explicit so codegen variations can never drop it
// (this closed the R15-class race; keep forever).
#define DRAIN asm volatile("s_waitcnt vmcnt(0)" ::: "memory")

__device__ __forceinline__ unsigned short f2bf(float f) {
  union { float f; unsigned u; } v; v.f = f;
  unsigned u = v.u;
  return (unsigned short)((u + 0x7fffu + ((u >> 16) & 1u)) >> 16);
}

__device__ __forceinline__ unsigned cvt_pk_bf16(float lo, float hi) {
  unsigned r;
  asm("v_cvt_pk_bf16_f32 %0, %1, %2" : "=v"(r) : "v"(lo), "v"(hi));
  return r;
}

__device__ __forceinline__ float shx32f(float x) { return __shfl_xor(x, 32, 64); }
__device__ __forceinline__ unsigned shx32u(unsigned x) {
  return (unsigned)__shfl_xor((int)x, 32, 64);
}

// async global -> LDS DMA, 16B per lane (dest = wave-uniform base + lane*16)
__device__ __forceinline__ void gload_lds16(const unsigned short* g, unsigned short* l) {
  __builtin_amdgcn_global_load_lds(
      (const __attribute__((address_space(1))) void*)g,
      (__attribute__((address_space(3))) void*)l, 16, 0, 0);
}

// ---------------------------------------------------------------------------
// Kernel 1: per-head QKV projection (unchanged, known-good).
// ---------------------------------------------------------------------------
__global__ __launch_bounds__(256) void qkv_proj_kernel(
    const float* __restrict__ x,
    const float* __restrict__ Wq, const float* __restrict__ bq,
    const float* __restrict__ Wk, const float* __restrict__ bk,
    const float* __restrict__ Wv, const float* __restrict__ bv,
    unsigned short* __restrict__ qo, unsigned short* __restrict__ ko,
    unsigned short* __restrict__ vto)
{
  const int blk = blockIdx.x;          // B*H*(C/128) = 1024
  const int ct = blk & 15;
  const int h  = (blk >> 4) & 15;
  const int b  = blk >> 8;
  const int wave = threadIdx.x >> 6;
  const int lane = threadIdx.x & 63;
  const int g = lane >> 4, l15 = lane & 15;

  const float* wqh = Wq + h * HDD * HDD;
  const float* wkh = Wk + h * HDD * HDD;
  const float* wvh = Wv + h * HDD * HDD;

  bf16x8 wqf[2][4], wkf[2][4], wvf[2][4];
  for (int c = 0; c < 2; ++c)
    for (int n = 0; n < 4; ++n) {
      const int e = 16 * n + l15;
      const int d0 = 32 * c + 8 * g;
      bf16x8 tq, tk, tv;
      for (int i = 0; i < 8; ++i) {
        tq[i] = (short)f2bf(wqh[(d0 + i) * HDD + e]);
        tk[i] = (short)f2bf(wkh[(d0 + i) * HDD + e]);
        tv[i] = (short)f2bf(wvh[(d0 + i) * HDD + e]);
      }
      wqf[c][n] = tq; wkf[c][n] = tk; wvf[c][n] = tv;
    }
  float bqv[4], bkv[4], bvv[4];
  for (int n = 0; n < 4; ++n) {
    bqv[n] = bq[h * HDD + 16 * n + l15];
    bkv[n] = bk[h * HDD + 16 * n + l15];
    bvv[n] = bv[h * HDD + 16 * n + l15];
  }

  const f32x4 fzero = {0.f, 0.f, 0.f, 0.f};
  const int c0 = ct * 128 + wave * 32;
  const int bh = b * HH + h;

  for (int mt = 0; mt < 2; ++mt) {
    const int crow_a = c0 + mt * 16 + l15;
    bf16x8 xa[2];
    for (int c = 0; c < 2; ++c) {
      const f32x4* xp = (const f32x4*)(x + (size_t)(b * CC + crow_a) * DD + h * HDD + 32 * c + 8 * g);
      f32x4 x0 = xp[0], x1 = xp[1];
      bf16x8 t;
      for (int i = 0; i < 4; ++i) { t[i] = (short)f2bf(x0[i]); t[4 + i] = (short)f2bf(x1[i]); }
      xa[c] = t;
    }
    f32x4 aq[4] = {fzero, fzero, fzero, fzero};
    f32x4 ak[4] = {fzero, fzero, fzero, fzero};
    f32x4 av[4] = {fzero, fzero, fzero, fzero};
    for (int c = 0; c < 2; ++c)
      for (int n = 0; n < 4; ++n) {
        aq[n] = __builtin_amdgcn_mfma_f32_16x16x32_bf16(xa[c], wqf[c][n], aq[n], 0, 0, 0);
        ak[n] = __builtin_amdgcn_mfma_f32_16x16x32_bf16(xa[c], wkf[c][n], ak[n], 0, 0, 0);
        av[n] = __builtin_amdgcn_mfma_f32_16x16x32_bf16(xa[c], wvf[c][n], av[n], 0, 0, 0);
      }
    const int crow_d = c0 + mt * 16 + 4 * g;
    for (int n = 0; n < 4; ++n) {
      const int e = 16 * n + l15;
      ushort4_t vpack;
      for (int r = 0; r < 4; ++r) {
        const int cr = crow_d + r;
        qo[((size_t)bh * CC + cr) * HDD + e] = f2bf((aq[n][r] + bqv[n]) * SCALE_LOG2E);
        ko[((size_t)bh * CC + cr) * HDD + e] = f2bf(ak[n][r] + bkv[n]);
        vpack[r] = f2bf(av[n][r] + bvv[n]);
      }
      *(ushort4_t*)(vto + ((size_t)bh * HDD + e) * CC + crow_d) = vpack;
    }
  }
}

// ---------------------------------------------------------------------------
// Kernel 2: flash attention — R16 body (passed, 190.9us, DRAIN race-closure).
// Round-17 single change: __launch_bounds__(256,2) -> (256,4). Occupancy
// experiment re-run now that DRAIN closes the R15-class race. VGPR 72 <= 128
// cap (no spill risk); 4 x 32KB = 128KB <= 160KB LDS/CU.
// ---------------------------------------------------------------------------
#define STAGE(CUR, SS) do {                                                    \
  _Pragma("unroll") for (int _i = 0; _i < 4; ++_i)                             \
    gload_lds16(ssrc[_i] + (SS) * sadv[_i], sdst[_i] + (CUR) * 8192);          \
} while (0)

#define KREAD(DST, BASE, SUB) do {                                             \
  const int _row = (SUB) * 32 + l31;                                           \
  _Pragma("unroll") for (int _c = 0; _c < 4; ++_c)                             \
    DST[_c] = *(const bf16x8*)((BASE) + _row * 64 + (((2 * _c + hi) ^ (_row & 7)) * 8)); \
} while (0)

#define VREAD(DST, BASE, SUB) do {                                             \
  _Pragma("unroll") for (int _e = 0; _e < 2; ++_e)                             \
  _Pragma("unroll") for (int _t = 0; _t < 2; ++_t) {                           \
    const int _row = 32 * _e + l31;                                            \
    DST[_e * 2 + _t] = *(const bf16x8*)((BASE) + 4096 + _row * 64 +            \
                         (((4 * (SUB) + 2 * _t + hi) ^ (_row & 7)) * 8));      \
  }                                                                            \
} while (0)

#define FLASH32(KF, VF) do {                                                   \
  f32x16 s = {};                                                               \
  __builtin_amdgcn_s_setprio(1);                                               \
  _Pragma("unroll") for (int c = 0; c < 4; ++c)                                \
    s = __builtin_amdgcn_mfma_f32_32x32x16_bf16(KF[c], qf[c], s, 0, 0, 0);     \
  __builtin_amdgcn_s_setprio(0);                                               \
  float p[16]; float rs = 0.f;                                                 \
  _Pragma("unroll") for (int i = 0; i < 16; ++i) {                             \
    p[i] = __builtin_amdgcn_exp2f(s[i]); rs += p[i];                           \
  }                                                                            \
  unsigned pa = cvt_pk_bf16(p[0], p[1]),  pb = cvt_pk_bf16(p[2], p[3]);        \
  unsigned pc = cvt_pk_bf16(p[4], p[5]),  pd = cvt_pk_bf16(p[6], p[7]);        \
  unsigned pe = cvt_pk_bf16(p[8], p[9]),  pf_ = cvt_pk_bf16(p[10], p[11]);     \
  unsigned pg = cvt_pk_bf16(p[12], p[13]), ph = cvt_pk_bf16(p[14], p[15]);     \
  unsigned spa = shx32u(pa), spb = shx32u(pb), spc = shx32u(pc), spd = shx32u(pd); \
  unsigned spe = shx32u(pe), spf = shx32u(pf_), spg = shx32u(pg), sph = shx32u(ph); \
  unsigned w00 = hi ? spc : pa, w01 = hi ? spd : pb;                           \
  unsigned w02 = hi ? pc : spa, w03 = hi ? pd : spb;                           \
  unsigned w10 = hi ? spg : pe, w11 = hi ? sph : pf_;                          \
  unsigned w12 = hi ? pg : spe, w13 = hi ? ph : spf;                           \
  uint4v u0 = {w00, w01, w02, w03}, u1 = {w10, w11, w12, w13};                 \
  bf16x8 pfr0 = __builtin_bit_cast(bf16x8, u0);                                \
  bf16x8 pfr1 = __builtin_bit_cast(bf16x8, u1);                                \
  rs += shx32f(rs);                                                            \
  l += rs;                                                                     \
  __builtin_amdgcn_s_setprio(1);                                               \
  acc0 = __builtin_amdgcn_mfma_f32_32x32x16_bf16(VF[0], pfr0, acc0, 0, 0, 0);  \
  acc0 = __builtin_amdgcn_mfma_f32_32x32x16_bf16(VF[1], pfr1, acc0, 0, 0, 0);  \
  acc1 = __builtin_amdgcn_mfma_f32_32x32x16_bf16(VF[2], pfr0, acc1, 0, 0, 0);  \
  acc1 = __builtin_amdgcn_mfma_f32_32x32x16_bf16(VF[3], pfr1, acc1, 0, 0, 0);  \
  __builtin_amdgcn_s_setprio(0);                                               \
} while (0)

__global__ __launch_bounds__(256, 4) void flash_fwd_kernel(
    const unsigned short* __restrict__ qw, const unsigned short* __restrict__ kw,
    const unsigned short* __restrict__ vtw,
    float* __restrict__ out, float* __restrict__ lse)
{
  __shared__ __align__(16) unsigned short slds[2][8192];   // 2 x (K 8KB | V 8KB)
  // XCD-chunked remap: grid 1024, 8 XCDs, 128 blocks/XCD chunk (bijective)
  const int blk = (blockIdx.x & 7) * 128 + (blockIdx.x >> 3);
  const int qt = blk & 15;
  const int h  = (blk >> 4) & 15;
  const int b  = blk >> 8;
  const int wave = threadIdx.x >> 6;
  const int lane = threadIdx.x & 63;
  const int l31 = lane & 31, hi = lane >> 5;
  const int bh = b * HH + h;
  const int q0 = qt * 128 + wave * 32;

  const unsigned short* qbh = qw + (size_t)bh * CC * HDD;
  const unsigned short* kbh = kw + (size_t)bh * CC * HDD;
  const unsigned short* vbh = vtw + (size_t)bh * HDD * CC;

  bf16x8 qf[4];
  for (int c = 0; c < 4; ++c)
    qf[c] = *(const bf16x8*)(qbh + (q0 + l31) * HDD + 16 * c + 8 * hi);

  const unsigned short* ssrc[4];
  int sadv[4];
  unsigned short* sdst[4];
#pragma unroll
  for (int i = 0; i < 4; ++i) {
    const int L = (wave * 4 + i) * 1024 + lane * 16;   // byte in 16KB tile
    const int tile = L >> 13;                           // 0 = K, 1 = V
    const int t = L & 8191;
    const int row = t >> 7;
    const int sch = ((t >> 4) & 7) ^ (row & 7);
    if (tile == 0) { ssrc[i] = kbh + row * HDD + sch * 8;        sadv[i] = 64 * HDD; }
    else           { ssrc[i] = vbh + (size_t)row * CC + sch * 8; sadv[i] = 64; }
    sdst[i] = &slds[0][0] + (wave * 4 + i) * 512;      // ushort units (1KB)
  }

  f32x16 acc0 = {}, acc1 = {};
  float l = 0.f;

  STAGE(0, 0);
  DRAIN;
  __syncthreads();
  int cur = 0;
  for (int ss = 0; ss < 32; ++ss) {
    if (ss != 31) STAGE(cur ^ 1, ss + 1);
    const unsigned short* base = &slds[0][0] + cur * 8192;
    bf16x8 kf[4], vf[4];
    KREAD(kf, base, 0);
    VREAD(vf, base, 0);
    FLASH32(kf, vf);
    KREAD(kf, base, 1);
    VREAD(vf, base, 1);
    FLASH32(kf, vf);
    DRAIN;
    __syncthreads();
    cur ^= 1;
  }

  const float rl = __builtin_amdgcn_rcpf(l);
  for (int i = 0; i < 16; ++i) { acc0[i] *= rl; acc1[i] *= rl; }
  float* orow = out + (size_t)(b * CC + q0 + l31) * DD + h * HDD;
  for (int j = 0; j < 4; ++j) {
    f32x4 v0, v1;
    for (int t = 0; t < 4; ++t) { v0[t] = acc0[4 * j + t]; v1[t] = acc1[4 * j + t]; }
    *(f32x4*)(orow + 4 * hi + 8 * j) = v0;
    *(f32x4*)(orow + 32 + 4 * hi + 8 * j) = v1;
  }
  if (hi == 0)
    lse[(size_t)bh * CC + q0 + l31] = __builtin_amdgcn_logf(l) + 4.0f;  // + log2(H)
}

// ---------------------------------------------------------------------------
// Kernel 3: attn_mean — R16 body (passed), unchanged.
// ---------------------------------------------------------------------------
#define AMK_LDSU 20480  // ushorts per buffer: K 16384 + Q 4096

#define ASTAGE(BUF, H) do {                                                    \
  _Pragma("unroll") for (int _i = 0; _i < 10; ++_i)                            \
    gload_lds16(asrc[_i] + (size_t)(H) * (CC * HDD), adst[_i] + (BUF) * AMK_LDSU); \
} while (0)

#define ATILE(QF, KF, AP, LS) do {                                             \
  f32x16 s_ = {};                                                              \
  _Pragma("unroll") for (int c = 0; c < 4; ++c)                                \
    s_ = __builtin_amdgcn_mfma_f32_32x32x16_bf16(QF[c], KF[c], s_, 0, 0, 0);   \
  _Pragma("unroll") for (int r = 0; r < 16; ++r)                               \
    AP[r] += __builtin_amdgcn_exp2f(s_[r] - LS[r]);                            \
} while (0)

__global__ __launch_bounds__(256, 2) void attn_mean_kernel(
    const unsigned short* __restrict__ qw, const unsigned short* __restrict__ kw,
    const float* __restrict__ lse, float* __restrict__ amean)
{
  __shared__ __align__(16) unsigned short slds[2][AMK_LDSU];
  // XCD-chunked remap: grid 1024 (bijective)
  const int blk = (blockIdx.x & 7) * 128 + (blockIdx.x >> 3);
  const int kvg = blk & 7;
  const int qt  = (blk >> 3) & 31;
  const int b   = blk >> 8;
  const int tid  = threadIdx.x;
  const int wave = tid >> 6;
  const int lane = tid & 63;
  const int l31 = lane & 31, hi = lane >> 5;
  const int q0 = qt * 64;
  const int kvb = kvg * 256;
  const int kv0 = kvb + wave * 64;

  const unsigned short* qb0 = qw + (size_t)(b * HH) * CC * HDD;  // head 0
  const unsigned short* kb0 = kw + (size_t)(b * HH) * CC * HDD;

  const unsigned short* asrc[10];
  unsigned short* adst[10];
#pragma unroll
  for (int i = 0; i < 10; ++i) {
    const int L = (i * 256 + tid) * 16;        // byte offset in 40KB tile
    if (L < 32768) {                            // K region: row=kvb+L/128
      const int row = L >> 7;
      const int ch = ((L >> 4) & 7) ^ (row & 7);
      asrc[i] = kb0 + (kvb + row) * HDD + ch * 8;
    } else {                                    // Q region: row=q0+Lq/128
      const int Lq = L - 32768;
      const int row = Lq >> 7;
      const int ch = ((Lq >> 4) & 7) ^ (row & 7);
      asrc[i] = qb0 + (q0 + row) * HDD + ch * 8;
    }
    adst[i] = &slds[0][0] + i * 2048 + wave * 512;   // ushort units
  }

  f32x16 ap00 = {}, ap01 = {}, ap10 = {}, ap11 = {};

  ASTAGE(0, 0);
  DRAIN;
  __syncthreads();
  int cur = 0;
  for (int h = 0; h < HH; ++h) {
    if (h != HH - 1) ASTAGE(cur ^ 1, h + 1);
    const float* lp = lse + (size_t)(b * HH + h) * CC + q0;
    float ls0[16], ls1[16];
#pragma unroll
    for (int r = 0; r < 16; ++r) {
      const int qr = (r & 3) + 8 * (r >> 2) + 4 * hi;
      ls0[r] = lp[qr];
      ls1[r] = lp[32 + qr];
    }
    const unsigned short* base = &slds[0][0] + cur * AMK_LDSU;
    bf16x8 qf0[4], qf1[4], kf0[4], kf1[4];
#pragma unroll
    for (int c = 0; c < 4; ++c) {
      const int qrow0 = l31, qrow1 = 32 + l31;
      const int krow0 = wave * 64 + l31, krow1 = wave * 64 + 32 + l31;
      qf0[c] = *(const bf16x8*)(base + 16384 + qrow0 * 64 + (((2 * c + hi) ^ (qrow0 & 7)) * 8));
      qf1[c] = *(const bf16x8*)(base + 16384 + qrow1 * 64 + (((2 * c + hi) ^ (qrow1 & 7)) * 8));
      kf0[c] = *(const bf16x8*)(base + krow0 * 64 + (((2 * c + hi) ^ (krow0 & 7)) * 8));
      kf1[c] = *(const bf16x8*)(base + krow1 * 64 + (((2 * c + hi) ^ (krow1 & 7)) * 8));
    }
    ATILE(qf0, kf0, ap00, ls0);
    ATILE(qf0, kf1, ap01, ls0);
    ATILE(qf1, kf0, ap10, ls1);
    ATILE(qf1, kf1, ap11, ls1);
    DRAIN;
    __syncthreads();
    cur ^= 1;
  }

  for (int r = 0; r < 16; ++r) {
    const int qr = (r & 3) + 8 * (r >> 2) + 4 * hi;
    const size_t row0 = (size_t)(b * CC + q0 + qr) * CC;
    const size_t row1 = row0 + (size_t)32 * CC;
    amean[row0 + kv0 + l31] = ap00[r];
    amean[row0 + kv0 + 32 + l31] = ap01[r];
    amean[row1 + kv0 + l31] = ap10[r];
    amean[row1 + kv0 + 32 + l31] = ap11[r];
  }
}

extern "C" void kernel_launch(void* const* d_in, const int* in_sizes, int n_in,
                              void* d_out, int out_size, void* d_ws, size_t ws_size,
                              hipStream_t stream) {
  const float* x  = (const float*)d_in[0];
  const float* Wq = (const float*)d_in[1];
  const float* bq = (const float*)d_in[2];
  const float* Wk = (const float*)d_in[3];
  const float* bk = (const float*)d_in[4];
  const float* Wv = (const float*)d_in[5];
  const float* bv = (const float*)d_in[6];
  float* out = (float*)d_out;
  float* amean = out + (size_t)BB * CC * DD;

  const size_t nqkv = (size_t)BB * HH * CC * HDD;
  unsigned short* qws  = (unsigned short*)d_ws;
  unsigned short* kws  = qws + nqkv;
  unsigned short* vtws = kws + nqkv;
  float* lse = (float*)(vtws + nqkv);

  qkv_proj_kernel<<<BB * HH * (CC / 128), 256, 0, stream>>>(
      x, Wq, bq, Wk, bk, Wv, bv, qws, kws, vtws);
  flash_fwd_kernel<<<BB * HH * (CC / 128), 256, 0, stream>>>(
      qws, kws, vtws, out, lse);
  attn_mean_kernel<<<BB * (CC / 64) * (CC / 256), 256, 0, stream>>>(
      qws, kws, lse, amean);
}